// Round 4
// baseline (29243.390 us; speedup 1.0000x reference)
//
#include <hip/hip_runtime.h>

// MANN/NTM encoder, MI355X persistent-kernel, round 4.
// vs r3: volatile (which forces s_waitcnt vmcnt(0) per access -> ~50 serialized
// L3 round trips/step) replaced by RELAXED system-scope atomics (same sc0 sc1
// L2-bypass, no forced waits -> all loads concurrent). h/r packed bf16 hi/lo in
// u32 (half the coherent bytes, shift-only unpack). Pair exchanges use
// tag-carried u64 {data,tag} polls (no flag+drain round trips). A-phase h/r
// loads issued flat up front (one latency exposure); emb from prepacked bf16.

#define T_STEPS 256
#define BSZ     128
#define IDIM    512
#define CDIM    512
#define MW      64
#define G4      2048
#define ODIM    576

typedef unsigned short u16;
typedef unsigned int   u32;
typedef unsigned long long u64;
typedef short  short8  __attribute__((ext_vector_type(8)));
typedef float  floatx4 __attribute__((ext_vector_type(4)));

__device__ __forceinline__ float bf2f(u16 h){ return __uint_as_float(((u32)h)<<16); }
__device__ __forceinline__ u16   f2bf(float f){ u32 u = __float_as_uint(f); return (u16)((u + 0x7fffu + ((u>>16)&1u))>>16); }
__device__ __forceinline__ float sigm(float x){ return 1.f/(1.f+__expf(-x)); }
__device__ __forceinline__ u32   packhl(float v){ u16 hi=f2bf(v); u16 lo=f2bf(v-bf2f(hi)); return (u32)hi | ((u32)lo<<16); }

// coherent-point ops: relaxed system scope = sc0 sc1, NO serializing waitcnt
__device__ __forceinline__ u32  ldc32(const u32* p){ return __hip_atomic_load((u32*)p, __ATOMIC_RELAXED, __HIP_MEMORY_SCOPE_SYSTEM); }
__device__ __forceinline__ u64  ldc64(const u64* p){ return __hip_atomic_load((u64*)p, __ATOMIC_RELAXED, __HIP_MEMORY_SCOPE_SYSTEM); }
__device__ __forceinline__ void stc32(u32* p, u32 v){ __hip_atomic_store(p, v, __ATOMIC_RELAXED, __HIP_MEMORY_SCOPE_SYSTEM); }
__device__ __forceinline__ void stc64(u64* p, u64 v){ __hip_atomic_store(p, v, __ATOMIC_RELAXED, __HIP_MEMORY_SCOPE_SYSTEM); }
__device__ __forceinline__ void flag_set(u32* p, u32 v){ __hip_atomic_store(p, v, __ATOMIC_RELAXED, __HIP_MEMORY_SCOPE_SYSTEM); }
__device__ __forceinline__ void flag_wait(u32* p, u32 v){
    while (__hip_atomic_load(p, __ATOMIC_RELAXED, __HIP_MEMORY_SCOPE_SYSTEM) < v)
        __builtin_amdgcn_s_sleep(1);
}
__device__ __forceinline__ u64 poll64(const u64* p, u32 tag){
    u64 v = ldc64(p);
    while ((u32)v != tag){ __builtin_amdgcn_s_sleep(1); v = ldc64(p); }
    return v;
}
#define VMDRAIN() asm volatile("s_waitcnt vmcnt(0)" ::: "memory")

// unpack 8 packed hi/lo u32 (as 4 u64) into hi-frag and lo-frag
__device__ __forceinline__ void unpk8(const u64* x, short8& hh, short8& ll){
    union { short8 s; u16 u[8]; } H, L;
    #pragma unroll
    for (int i=0;i<8;i++){
        u32 wv = (u32)(x[i>>1] >> ((i&1)*32));
        H.u[i] = (u16)wv; L.u[i] = (u16)(wv>>16);
    }
    hh=H.s; ll=L.s;
}

// ---------------- prep kernels ----------------

__global__ void prep_embs(const float* __restrict__ e, u16* __restrict__ o){
    int i = blockIdx.x*256 + threadIdx.x;            // 4194304 threads
    float4 v = ((const float4*)e)[i];
    u32 lo = (u32)f2bf(v.x) | ((u32)f2bf(v.y)<<16);
    u32 hi = (u32)f2bf(v.z) | ((u32)f2bf(v.w)<<16);
    *(uint2*)&o[(size_t)i*4] = make_uint2(lo,hi);
}

// W = [w_ih | w_hh] -> bf16 hi/lo, gate-interleaved cols (j=4n+g), k-major-8
__global__ void prep_wt(const float* __restrict__ wih, const float* __restrict__ whh,
                        const float* __restrict__ bih, const float* __restrict__ bhh,
                        u16* __restrict__ WT, float* __restrict__ biasp){
    int idx = blockIdx.x*256 + threadIdx.x;          // 136*2048 = 278528
    if (idx >= 136*G4) return;
    int j  = idx & (G4-1);
    int kg = idx >> 11;
    int ro = (j&3)*512 + (j>>2);
    u32 ohi[4], olo[4];
    #pragma unroll
    for (int p=0;p<4;p++){
        int k0 = kg*8 + p*2;
        float v0 = (k0   < 576) ? wih[ro*576 + k0  ] : whh[ro*512 + k0   - 576];
        float v1 = (k0+1 < 576) ? wih[ro*576 + k0+1] : whh[ro*512 + k0+1 - 576];
        u16 h0b = f2bf(v0), h1b = f2bf(v1);
        u16 l0b = f2bf(v0 - bf2f(h0b)), l1b = f2bf(v1 - bf2f(h1b));
        ohi[p] = (u32)h0b | ((u32)h1b<<16);
        olo[p] = (u32)l0b | ((u32)l1b<<16);
    }
    *(uint4*)&WT[(size_t)idx*16]     = make_uint4(ohi[0],ohi[1],ohi[2],ohi[3]);
    *(uint4*)&WT[(size_t)idx*16 + 8] = make_uint4(olo[0],olo[1],olo[2],olo[3]);
    if (idx < G4) biasp[j] = bih[ro] + bhh[ro];
}

__global__ void prep_misc(const float* __restrict__ Wrk, const float* __restrict__ Wwk,
                          const float* __restrict__ We,  const float* __restrict__ Wa,
                          const float* __restrict__ brk, const float* __restrict__ bwk,
                          const float* __restrict__ be,  const float* __restrict__ ba,
                          const float* __restrict__ h0,  const float* __restrict__ r0,
                          u16* __restrict__ Wk, float* __restrict__ kb,
                          u32* __restrict__ hpk, u32* __restrict__ xrpk,
                          u32* __restrict__ hflag, u32* __restrict__ rflag){
    int idx = blockIdx.x*256 + threadIdx.x;          // grid 512*256 = 131072
    if (idx < 32768) {
        int d4 = idx >> 8, k = idx & 255;
        const float* src = (k<64)? Wrk + k*512 : (k<128)? Wwk + (k-64)*512
                         : (k<192)? We + (k-128)*512 : Wa + (k-192)*512;
        u32 a = (u32)f2bf(src[d4*4+0]) | ((u32)f2bf(src[d4*4+1])<<16);
        u32 b = (u32)f2bf(src[d4*4+2]) | ((u32)f2bf(src[d4*4+3])<<16);
        *(uint2*)&Wk[(size_t)idx*4] = make_uint2(a,b);
    } else if (idx < 33024) {
        int k = idx - 32768;
        kb[k] = (k<64)? brk[k] : (k<128)? bwk[k-64] : (k<192)? be[k-128] : ba[k-192];
    } else if (idx < 98560) {
        int i = idx - 33024;
        hpk[65536 + i] = packhl(h0[i & 511]);        // slot 1 = h_{-1}
    } else if (idx < 106752) {
        int i = idx - 98560;
        xrpk[i] = packhl(r0[i & 63]);
    } else if (idx < 107776) {
        hflag[idx - 106752] = 0u;
    } else if (idx < 109824) {
        rflag[idx - 107776] = 0u;
    }
}

// ---------------- persistent kernel ----------------

__device__ __forceinline__ float blkMax(float v, float* red){
    #pragma unroll
    for (int o=32;o;o>>=1) v = fmaxf(v, __shfl_xor(v,o,64));
    if ((threadIdx.x & 63) == 0) red[threadIdx.x>>6] = v;
    __syncthreads();
    float r = red[0];
    #pragma unroll
    for (int i=1;i<8;i++) r = fmaxf(r, red[i]);
    return r;
}
__device__ __forceinline__ float blkSum(float v, float* red){
    #pragma unroll
    for (int o=32;o;o>>=1) v += __shfl_xor(v,o,64);
    if ((threadIdx.x & 63) == 0) red[threadIdx.x>>6] = v;
    __syncthreads();
    float r = red[0];
    #pragma unroll
    for (int i=1;i<8;i++) r += red[i];
    return r;
}

#define BSTEP ((size_t)(4*G4*16))

__launch_bounds__(512)
__global__ void mann_persist(const u16* __restrict__ embsb, const u16* __restrict__ WT,
                             const float* __restrict__ biasp, const u16* __restrict__ Wk,
                             const float* __restrict__ kbias,
                             u32* __restrict__ hpk, u32* __restrict__ xrpk,
                             const float* __restrict__ mem0, const float* __restrict__ c0,
                             float* __restrict__ out, u64* __restrict__ pair,
                             u32* __restrict__ hflag, u32* __restrict__ rflag){
    __shared__ float mem_lds[512*65];   // stride 65: 2-way max (free)
    __shared__ float h_lds[512];
    __shared__ float emb_lds[512];
    __shared__ float keys_lds[256];     // k_r | k_w | e | a
    __shared__ float er_lds[512];       // + keys-GEMV scratch
    __shared__ float ew_lds[512];
    __shared__ float urp[512];
    __shared__ float red[32];
    __shared__ float xch[4];
    __shared__ u32   ha_lds[2048];      // A epilogue h staging (16b x 128n packed)

    const int w    = blockIdx.x;
    const int tid  = threadIdx.x;
    const int batch = ((w>>4)<<3) + (w&7);
    const int half  = (w>>3)&1;
    const int mate  = w ^ 8;
    const bool isA = (w < 32);
    const int bgrp = w >> 2, cgrp = w & 3;     // A: 16 batches x 512 packed cols
    const int lane = tid & 63, wv = tid >> 6;
    const int jl = lane & 15, q = lane >> 4;
    const int colbase = cgrp*512 + wv*64;

    float creg[16];
    if (isA) {
        #pragma unroll
        for (int tl=0; tl<4; ++tl) {
            float cv = c0[(colbase + tl*16 + jl) >> 2];
            creg[tl*4+0]=cv; creg[tl*4+1]=cv; creg[tl*4+2]=cv; creg[tl*4+3]=cv;
        }
    }

    {   // mem half -> LDS
        const float* src = mem0 + (size_t)(half*512)*64;
        for (int i = tid; i < 512*64; i += 512)
            mem_lds[(i>>6)*65 + (i&63)] = src[i];
    }
    __syncthreads();

    for (int t = 0; t < T_STEPS; ++t) {
        const u32 tag = (u32)(t+1);
        // ---------------- PHASE A ----------------
        if (isA) {
            if (tid < 16)      flag_wait(&rflag[(bgrp*16 + tid)*16], (u32)t);
            else if (tid < 20) flag_wait(&hflag[(bgrp*4 + (tid-16))*32], (u32)t);
            __syncthreads();

            const int bA = bgrp*16 + jl;
            const u16* ap0 = embsb + ((size_t)(t*BSZ + bA))*IDIM + q*8;
            const u64* h64 = (const u64*)(hpk + ((t+1)&1)*65536 + bA*CDIM);
            const u64* r64 = (const u64*)(xrpk + bA*MW);
            const u16* bp0 = WT + ((size_t)q*G4 + colbase + jl)*16;

            // issue ALL coherent loads up front (concurrent, one latency exposure)
            u64 hv[64], rvv[8];
            #pragma unroll
            for (int i=0;i<64;i++) hv[i] = ldc64(h64 + (i>>2)*16 + q*4 + (i&3));
            #pragma unroll
            for (int i=0;i<8;i++)  rvv[i] = ldc64(r64 + (i>>2)*16 + q*4 + (i&3));

            floatx4 acc[4] = {{0.f,0.f,0.f,0.f},{0.f,0.f,0.f,0.f},
                              {0.f,0.f,0.f,0.f},{0.f,0.f,0.f,0.f}};

            #pragma unroll
            for (int kk = 0; kk < 16; ++kk) {          // h_{t-1}: 3-term
                short8 ah, al; unpk8(&hv[kk*4], ah, al);
                const u16* bks = bp0 + (size_t)(18+kk)*BSTEP;
                #pragma unroll
                for (int tl = 0; tl < 4; ++tl) {
                    short8 bh = *(const short8*)(bks + tl*256);
                    short8 bl = *(const short8*)(bks + tl*256 + 8);
                    acc[tl] = __builtin_amdgcn_mfma_f32_16x16x32_bf16(ah, bh, acc[tl], 0,0,0);
                    acc[tl] = __builtin_amdgcn_mfma_f32_16x16x32_bf16(al, bh, acc[tl], 0,0,0);
                    acc[tl] = __builtin_amdgcn_mfma_f32_16x16x32_bf16(ah, bl, acc[tl], 0,0,0);
                }
            }
            #pragma unroll
            for (int kk = 0; kk < 2; ++kk) {           // r_{t-1}: 3-term
                short8 ah, al; unpk8(&rvv[kk*4], ah, al);
                const u16* bks = bp0 + (size_t)(16+kk)*BSTEP;
                #pragma unroll
                for (int tl = 0; tl < 4; ++tl) {
                    short8 bh = *(const short8*)(bks + tl*256);
                    short8 bl = *(const short8*)(bks + tl*256 + 8);
                    acc[tl] = __builtin_amdgcn_mfma_f32_16x16x32_bf16(ah, bh, acc[tl], 0,0,0);
                    acc[tl] = __builtin_amdgcn_mfma_f32_16x16x32_bf16(al, bh, acc[tl], 0,0,0);
                    acc[tl] = __builtin_amdgcn_mfma_f32_16x16x32_bf16(ah, bl, acc[tl], 0,0,0);
                }
            }
            #pragma unroll 2
            for (int ks = 0; ks < 16; ++ks) {          // emb (bf16, cached): 2-term
                short8 af = *(const short8*)(ap0 + ks*32);
                const u16* bks = bp0 + (size_t)ks*BSTEP;
                #pragma unroll
                for (int tl = 0; tl < 4; ++tl) {
                    short8 bh = *(const short8*)(bks + tl*256);
                    short8 bl = *(const short8*)(bks + tl*256 + 8);
                    acc[tl] = __builtin_amdgcn_mfma_f32_16x16x32_bf16(af, bh, acc[tl], 0,0,0);
                    acc[tl] = __builtin_amdgcn_mfma_f32_16x16x32_bf16(af, bl, acc[tl], 0,0,0);
                }
            }

            // LSTM epilogue: 4 lanes = i,f,g,o of one n; g==0 lane stages h
            #pragma unroll
            for (int tl = 0; tl < 4; ++tl) {
                int j = colbase + tl*16 + jl;
                int g = j & 3, n = j >> 2;
                float bias = biasp[j];
                #pragma unroll
                for (int rg = 0; rg < 4; ++rg) {
                    float gval = acc[tl][rg] + bias;
                    int base = lane & ~3;
                    float iv = __shfl(gval, base+0, 64);
                    float fv = __shfl(gval, base+1, 64);
                    float gv = __shfl(gval, base+2, 64);
                    float ov = __shfl(gval, base+3, 64);
                    float cn = sigm(fv)*creg[tl*4+rg] + sigm(iv)*tanhf(gv);
                    creg[tl*4+rg] = cn;
                    float hn = sigm(ov)*tanhf(cn);
                    if (g == 0) {
                        int b = bgrp*16 + q*4 + rg;
                        out[(size_t)(t*BSZ + b)*ODIM + n] = hn;   // normal store
                        ha_lds[(q*4+rg)*128 + (n - cgrp*128)] = packhl(hn);
                    }
                }
            }
            __syncthreads();
            // coalesced h publish: 2048 u32, 4 per thread
            #pragma unroll
            for (int i = 0; i < 4; ++i) {
                int idx = tid + i*512;
                int bl = idx >> 7, np = idx & 127;
                stc32(hpk + (t&1)*65536 + (bgrp*16 + bl)*CDIM + cgrp*128 + np, ha_lds[idx]);
            }
            VMDRAIN();
            __syncthreads();
            if (tid == 0) flag_set(&hflag[w*32], tag);
        }

        // ---------------- PHASE B (all 256 WGs) ----------------
        if (tid < 4) flag_wait(&hflag[((batch>>4)*4 + tid)*32], tag);
        __syncthreads();
        {
            u32 hw2 = ldc32(hpk + (t&1)*65536 + batch*CDIM + tid);
            h_lds[tid]   = bf2f((u16)hw2) + bf2f((u16)(hw2>>16));
            emb_lds[tid] = bf2f(embsb[((size_t)(t*BSZ + batch))*IDIM + tid]);
        }
        __syncthreads();

        // keys GEMV: 256 keys x 2 k-halves over 512 threads, Wk L2-resident
        {
            int key = tid & 255, kh = tid >> 8;
            const float* src = (key < 192) ? h_lds : emb_lds;
            const uint2* wp = (const uint2*)Wk;
            float a0=0.f, a1=0.f, a2=0.f, a3=0.f;
            int d0 = kh*256;
            #pragma unroll 8
            for (int dd = 0; dd < 256; dd += 4) {
                uint2 wvv = wp[((d0+dd)>>2)*256 + key];
                a0 += src[d0+dd+0]*bf2f((u16)(wvv.x & 0xffffu));
                a1 += src[d0+dd+1]*bf2f((u16)(wvv.x >> 16));
                a2 += src[d0+dd+2]*bf2f((u16)(wvv.y & 0xffffu));
                a3 += src[d0+dd+3]*bf2f((u16)(wvv.y >> 16));
            }
            er_lds[tid] = (a0+a1)+(a2+a3);
        }
        __syncthreads();
        if (tid < 256) {
            float acc = kbias[tid] + er_lds[tid] + er_lds[tid+256];
            if (tid >= 192)      acc = tanhf(acc);
            else if (tid >= 128) acc = sigm(acc);
            keys_lds[tid] = acc;
        }
        __syncthreads();

        // scores (thread = slot)
        float s_r = 0.f, s_w = 0.f;
        {
            const float* mr = &mem_lds[tid*65];
            #pragma unroll 8
            for (int m = 0; m < 64; ++m) {
                float mv = mr[m];
                s_r += mv * keys_lds[m];
                s_w += mv * keys_lds[64+m];
            }
        }
        float Mr = blkMax(s_r, red+0);
        float Mw = blkMax(s_w, red+8);
        float erv = __expf(s_r - Mr), ewv = __expf(s_w - Mw);
        er_lds[tid] = erv; ew_lds[tid] = ewv;
        float Sr = blkSum(erv, red+16);
        float Sw = blkSum(ewv, red+24);

        // pair stats exchange: tag-carried u64, one round trip, no fence
        u64* myp = pair + (size_t)w*128;
        const u64* thp = pair + (size_t)mate*128;
        if (tid < 4) {
            float sv = (tid==0)?Mr:(tid==1)?Mw:(tid==2)?Sr:Sw;
            stc64(myp + 64 + tid, ((u64)__float_as_uint(sv)<<32) | (u64)tag);
            u64 got = poll64(thp + 64 + tid, tag);
            xch[tid] = __uint_as_float((u32)(got>>32));
        }
        __syncthreads();
        float Mr_p = xch[0], Mw_p = xch[1], Sr_p = xch[2], Sw_p = xch[3];
        float Mr_g = fmaxf(Mr, Mr_p), Mw_g = fmaxf(Mw, Mw_p);
        float scr = __expf(Mr - Mr_g);
        float scw = __expf(Mw - Mw_g);
        float Sr_tot = Sr*scr + Sr_p*__expf(Mr_p - Mr_g);
        float Sw_tot = Sw*scw + Sw_p*__expf(Mw_p - Mw_g);
        float wsc = scw / Sw_tot;

        // fused read + erase/add update
        {
            int m = tid & 63, grp = tid >> 6;
            float em = keys_lds[128+m], am = keys_lds[192+m];
            float urv = 0.f;
            int n0 = grp*64;
            #pragma unroll 4
            for (int i = 0; i < 64; ++i) {
                int n = n0 + i;
                float mv = mem_lds[n*65 + m];
                urv += er_lds[n]*mv;
                float wn = ew_lds[n]*wsc;
                mem_lds[n*65+m] = mv*(1.f - wn*em) + wn*am;
            }
            urp[tid] = urv;
        }
        __syncthreads();
        float ur_tot = 0.f;
        if (tid < 64) {
            #pragma unroll
            for (int g2 = 0; g2 < 8; ++g2) ur_tot += urp[g2*64 + tid];
        }
        if (half == 1) {                               // partials: tag-carried u64
            if (tid < 64) stc64(myp + tid, ((u64)__float_as_uint(ur_tot*scr)<<32) | (u64)tag);
        } else {
            if (tid < 64) {
                u64 got = poll64(thp + tid, tag);
                float rv = (ur_tot*scr + __uint_as_float((u32)(got>>32))) / Sr_tot;
                out[(size_t)(t*BSZ + batch)*ODIM + 512 + tid] = rv;
                stc32(xrpk + batch*MW + tid, packhl(rv));
                VMDRAIN();                             // wave 0: all 64 lanes' stores done
                if (tid == 0) flag_set(&rflag[batch*16], tag);
            }
        }
    }
}

// ---------------- launch ----------------

#define OFF_EMBSB  0u
#define OFF_WT     33554432u
#define OFF_BIASP  42467328u
#define OFF_WK     42475520u
#define OFF_KBIAS  42737664u
#define OFF_HPK    42738688u
#define OFF_XRPK   43262976u
#define OFF_PAIR   43295744u
#define OFF_HFLAG  43557888u
#define OFF_RFLAG  43561984u
#define WS_NEED    43570176u

extern "C" void kernel_launch(void* const* d_in, const int* in_sizes, int n_in,
                              void* d_out, int out_size, void* d_ws, size_t ws_size,
                              hipStream_t stream) {
    if (ws_size < (size_t)WS_NEED) return;

    const float* embs = (const float*)d_in[0];
    const float* w_ih = (const float*)d_in[1];
    const float* w_hh = (const float*)d_in[2];
    const float* b_ih = (const float*)d_in[3];
    const float* b_hh = (const float*)d_in[4];
    const float* h0   = (const float*)d_in[5];
    const float* c0   = (const float*)d_in[6];
    const float* r0   = (const float*)d_in[7];
    const float* mem0 = (const float*)d_in[8];
    const float* Wrk  = (const float*)d_in[9];
    const float* brk  = (const float*)d_in[10];
    const float* Wwk  = (const float*)d_in[11];
    const float* bwk  = (const float*)d_in[12];
    const float* We   = (const float*)d_in[13];
    const float* be   = (const float*)d_in[14];
    const float* Wa   = (const float*)d_in[15];
    const float* ba   = (const float*)d_in[16];

    char* ws = (char*)d_ws;
    u16*   embsb = (u16*)  (ws + OFF_EMBSB);
    u16*   WT    = (u16*)  (ws + OFF_WT);
    float* biasp = (float*)(ws + OFF_BIASP);
    u16*   Wk    = (u16*)  (ws + OFF_WK);
    float* kbias = (float*)(ws + OFF_KBIAS);
    u32*   hpk   = (u32*)  (ws + OFF_HPK);
    u32*   xrpk  = (u32*)  (ws + OFF_XRPK);
    u64*   pair  = (u64*)  (ws + OFF_PAIR);
    u32*   hflag = (u32*)  (ws + OFF_HFLAG);
    u32*   rflag = (u32*)  (ws + OFF_RFLAG);
    float* outp  = (float*)d_out;

    hipLaunchKernelGGL(prep_embs, dim3(16384), dim3(256), 0, stream, embs, embsb);
    hipLaunchKernelGGL(prep_wt,   dim3(1088),  dim3(256), 0, stream,
                       w_ih, w_hh, b_ih, b_hh, WT, biasp);
    hipLaunchKernelGGL(prep_misc, dim3(512),   dim3(256), 0, stream,
                       Wrk, Wwk, We, Wa, brk, bwk, be, ba, h0, r0,
                       Wk, kbias, hpk, xrpk, hflag, rflag);

    const u16* embsb_c = embsb; const u16* WT_c = WT; const float* biasp_c = biasp;
    const u16* Wk_c = Wk; const float* kbias_c = kbias;
    const float* mem0_c = mem0; const float* c0_c = c0;
    void* kargs[] = { (void*)&embsb_c, (void*)&WT_c, (void*)&biasp_c, (void*)&Wk_c,
                      (void*)&kbias_c, (void*)&hpk, (void*)&xrpk, (void*)&mem0_c,
                      (void*)&c0_c, (void*)&outp, (void*)&pair,
                      (void*)&hflag, (void*)&rflag };
    hipLaunchCooperativeKernel((void*)mann_persist, dim3(256), dim3(512), kargs, 0, stream);
}